// Round 1
// baseline (481.137 us; speedup 1.0000x reference)
//
#include <hip/hip_runtime.h>
#include <math.h>

#define EPS 1e-5f
#define N0 1000
#define K1 500
#define K2 100
#define NE 32000

__device__ __forceinline__ float bnr(float h, float sc, float sh) {
    float v = fmaf(h, sc, sh);
    return v > 0.f ? v : 0.f;
}

// ---- init: zero the BN sum accumulators (912 floats) ----
__global__ void k_init(float* sums) {
    for (int i = threadIdx.x; i < 912; i += 256) sums[i] = 0.f;
}

// ---- layer0: (1000,3)->(1000,64) raw + channel sums ----
__global__ void k_lin0(const float* __restrict__ x, const float* __restrict__ w0,
                       const float* __restrict__ b0, float* __restrict__ h0,
                       float* __restrict__ sums0) {
    int t = threadIdx.x;
    int c = t & 63, ns = t >> 6;
    int nb = blockIdx.x * 128;
    float wa = w0[c * 3 + 0], wb = w0[c * 3 + 1], wc = w0[c * 3 + 2], bb = b0[c];
    float s = 0.f, q = 0.f;
    for (int j = 0; j < 32; ++j) {
        int n = nb + ns + 4 * j;
        if (n < N0) {
            float h = fmaf(wa, x[n * 3], fmaf(wb, x[n * 3 + 1], fmaf(wc, x[n * 3 + 2], bb)));
            h0[n * 64 + c] = h;
            s += h; q += h * h;
        }
    }
    __shared__ float rs[256], rq[256];
    rs[t] = s; rq[t] = q;
    __syncthreads();
    if (ns == 0) {
        atomicAdd(&sums0[c],      rs[c] + rs[c + 64] + rs[c + 128] + rs[c + 192]);
        atomicAdd(&sums0[64 + c], rq[c] + rq[c + 64] + rq[c + 128] + rq[c + 192]);
    }
}

// ---- layer1: bnrelu(h0) @ w1^T -> h1 raw + sums ----
__global__ void k_lin1(const float* __restrict__ h0, const float* __restrict__ w1,
                       const float* __restrict__ b1v, const float* __restrict__ g0,
                       const float* __restrict__ be0, const float* __restrict__ sums0,
                       float* __restrict__ h1, float* __restrict__ sums1) {
    __shared__ float xs[64][65];
    __shared__ float wsm[64][65];
    __shared__ float sc0[64], sh0[64];
    __shared__ float rs[256], rq[256];
    int t = threadIdx.x;
    int nb = blockIdx.x * 64;
    if (t < 64) {
        float mu = sums0[t] * (1.f / N0);
        float var = sums0[64 + t] * (1.f / N0) - mu * mu;
        float sc = g0[t] * rsqrtf(var + EPS);
        sc0[t] = sc; sh0[t] = be0[t] - mu * sc;
    }
    __syncthreads();
    for (int i = 0; i < 16; ++i) {
        int e = t + i * 256;
        int r = e >> 6, cc = e & 63;
        int n = nb + r;
        xs[r][cc] = (n < N0) ? bnr(h0[n * 64 + cc], sc0[cc], sh0[cc]) : 0.f;
        wsm[r][cc] = w1[e];
    }
    __syncthreads();
    int c = t & 63, ns = t >> 6;
    float s = 0.f, q = 0.f;
    for (int j = 0; j < 16; ++j) {
        int ln = ns + 4 * j;
        int n = nb + ln;
        if (n < N0) {
            float acc = b1v[c];
            #pragma unroll
            for (int k = 0; k < 64; ++k) acc = fmaf(xs[ln][k], wsm[c][k], acc);
            h1[n * 64 + c] = acc;
            s += acc; q += acc * acc;
        }
    }
    rs[t] = s; rq[t] = q;
    __syncthreads();
    if (ns == 0) {
        atomicAdd(&sums1[c],      rs[c] + rs[c + 64] + rs[c + 128] + rs[c + 192]);
        atomicAdd(&sums1[64 + c], rq[c] + rq[c + 64] + rq[c + 128] + rq[c + 192]);
    }
}

// ---- pool1 scores: t1 = x1.w_rel ; sc1 = x1.w_root + b ----
__global__ void k_score1(const float* __restrict__ h1, const float* __restrict__ sums1,
                         const float* __restrict__ g1, const float* __restrict__ be1,
                         const float* __restrict__ wrel, const float* __restrict__ wroot,
                         const float* __restrict__ pb,
                         float* __restrict__ t1, float* __restrict__ sc1) {
    __shared__ float sc[64], sh[64];
    int t = threadIdx.x;
    if (t < 64) {
        float mu = sums1[t] * (1.f / N0);
        float var = sums1[64 + t] * (1.f / N0) - mu * mu;
        float s = g1[t] * rsqrtf(var + EPS);
        sc[t] = s; sh[t] = be1[t] - mu * s;
    }
    __syncthreads();
    int n = blockIdx.x * 256 + t;
    if (n < N0) {
        float dr = 0.f, dt = 0.f;
        for (int k = 0; k < 64; ++k) {
            float v = bnr(h1[n * 64 + k], sc[k], sh[k]);
            dr = fmaf(v, wrel[k], dr);
            dt = fmaf(v, wroot[k], dt);
        }
        t1[n] = dr;
        sc1[n] = dt + pb[0];
    }
}

__global__ void k_scatter1(const int* __restrict__ ei, const float* __restrict__ ea,
                           const float* __restrict__ t1, float* __restrict__ sc1) {
    int e = blockIdx.x * 256 + threadIdx.x;
    if (e < NE) {
        atomicAdd(&sc1[ei[NE + e]], ea[e] * t1[ei[e]]);
    }
}

// ---- pool1 rank+select: xp1[rank] = x1[n]*tanh(s) ----
__global__ void k_rank1(const float* __restrict__ sc1, const float* __restrict__ h1,
                        const float* __restrict__ sums1, const float* __restrict__ g1,
                        const float* __restrict__ be1,
                        float* __restrict__ xp1, int* __restrict__ keep, int* __restrict__ nidx) {
    __shared__ float ss[N0];
    __shared__ float sc[64], sh[64];
    int t = threadIdx.x;
    if (t < 64) {
        float mu = sums1[t] * (1.f / N0);
        float var = sums1[64 + t] * (1.f / N0) - mu * mu;
        float s = g1[t] * rsqrtf(var + EPS);
        sc[t] = s; sh[t] = be1[t] - mu * s;
    }
    for (int i = t; i < N0; i += 256) ss[i] = sc1[i];
    __syncthreads();
    int n = blockIdx.x * 256 + t;
    if (n < N0) {
        float s = ss[n];
        int r = 0;
        for (int m = 0; m < N0; ++m) {
            float sm = ss[m];
            r += (sm > s) || (sm == s && m < n);
        }
        keep[n] = (r < K1) ? 1 : 0;
        nidx[n] = (r < K1) ? r : 0;
        if (r < K1) {
            float tn = tanhf(s);
            for (int c = 0; c < 64; ++c)
                xp1[r * 64 + c] = bnr(h1[n * 64 + c], sc[c], sh[c]) * tn;
        }
    }
}

// ---- fused: layer2a matmul (blocks 0..7) + edge remap (blocks 8..132) ----
__global__ void k_lin2a_remap(const float* __restrict__ xp1, const float* __restrict__ w2a,
                              const float* __restrict__ b2a, float* __restrict__ h2a,
                              float* __restrict__ sums2a,
                              const int* __restrict__ ei, const float* __restrict__ ea,
                              const int* __restrict__ keep, const int* __restrict__ nidx,
                              int* __restrict__ nsrc, int* __restrict__ ndst,
                              float* __restrict__ new_ew) {
    __shared__ float xs[64][65];
    __shared__ float wsm[128][65];
    __shared__ float rs[256], rq[256];
    int b = blockIdx.x;
    int t = threadIdx.x;
    if (b < 8) {
        int nb = b * 64;
        for (int i = 0; i < 16; ++i) {
            int e = t + i * 256;
            int r = e >> 6, cc = e & 63;
            int n = nb + r;
            xs[r][cc] = (n < K1) ? xp1[n * 64 + cc] : 0.f;
        }
        for (int i = 0; i < 32; ++i) {
            int e = t + i * 256;
            wsm[e >> 6][e & 63] = w2a[e];
        }
        __syncthreads();
        int c = t & 127, ns = t >> 7;
        float s = 0.f, q = 0.f;
        for (int j = 0; j < 32; ++j) {
            int ln = ns + 2 * j;
            int n = nb + ln;
            if (n < K1) {
                float acc = b2a[c];
                #pragma unroll
                for (int k = 0; k < 64; ++k) acc = fmaf(xs[ln][k], wsm[c][k], acc);
                h2a[n * 128 + c] = acc;
                s += acc; q += acc * acc;
            }
        }
        rs[t] = s; rq[t] = q;
        __syncthreads();
        if (ns == 0) {
            atomicAdd(&sums2a[c],       rs[c] + rs[c + 128]);
            atomicAdd(&sums2a[128 + c], rq[c] + rq[c + 128]);
        }
    } else {
        int e = (b - 8) * 256 + t;
        if (e < NE) {
            int s = ei[e], d = ei[NE + e];
            bool v = keep[s] && keep[d];
            nsrc[e] = v ? nidx[s] : 0;
            ndst[e] = v ? nidx[d] : 0;
            new_ew[e] = v ? ea[e] : 0.f;
        }
    }
}

// ---- layer2b: bnrelu(h2a) @ w2b^T -> h2b raw + sums. 25 nodes/block, thread=out channel ----
__global__ void k_lin2b(const float* __restrict__ h2a, const float* __restrict__ sums2a,
                        const float* __restrict__ g2a, const float* __restrict__ be2a,
                        const float* __restrict__ w2b, const float* __restrict__ b2b,
                        float* __restrict__ h2b, float* __restrict__ sums2b) {
    __shared__ float xs[25][130];
    __shared__ float sc[128], sh[128];
    int t = threadIdx.x;
    if (t < 128) {
        float mu = sums2a[t] * (1.f / K1);
        float var = sums2a[128 + t] * (1.f / K1) - mu * mu;
        float s = g2a[t] * rsqrtf(var + EPS);
        sc[t] = s; sh[t] = be2a[t] - mu * s;
    }
    __syncthreads();
    int nb = blockIdx.x * 25;
    for (int i = t; i < 25 * 128; i += 256) {
        int r = i >> 7, cc = i & 127;
        int n = nb + r;
        xs[r][cc] = (n < K1) ? bnr(h2a[n * 128 + cc], sc[cc], sh[cc]) : 0.f;
    }
    __syncthreads();
    if (t < 200) {
        int c = t;
        float acc[25];
        float bb = b2b[c];
        #pragma unroll
        for (int r = 0; r < 25; ++r) acc[r] = bb;
        for (int k = 0; k < 128; ++k) {
            float wv = w2b[c * 128 + k];
            #pragma unroll
            for (int r = 0; r < 25; ++r) acc[r] = fmaf(xs[r][k], wv, acc[r]);
        }
        float s = 0.f, q = 0.f;
        for (int r = 0; r < 25; ++r) {
            int n = nb + r;
            if (n < K1) {
                h2b[n * 200 + c] = acc[r];
                s += acc[r]; q += acc[r] * acc[r];
            }
        }
        atomicAdd(&sums2b[c], s);
        atomicAdd(&sums2b[200 + c], q);
    }
}

// ---- pool2 scores ----
__global__ void k_score2(const float* __restrict__ h2b, const float* __restrict__ sums2b,
                         const float* __restrict__ g2b, const float* __restrict__ be2b,
                         const float* __restrict__ wrel, const float* __restrict__ wroot,
                         const float* __restrict__ pb,
                         float* __restrict__ t2, float* __restrict__ sc2) {
    __shared__ float sc[200], sh[200];
    int t = threadIdx.x;
    if (t < 200) {
        float mu = sums2b[t] * (1.f / K1);
        float var = sums2b[200 + t] * (1.f / K1) - mu * mu;
        float s = g2b[t] * rsqrtf(var + EPS);
        sc[t] = s; sh[t] = be2b[t] - mu * s;
    }
    __syncthreads();
    int n = blockIdx.x * 256 + t;
    if (n < K1) {
        float dr = 0.f, dt = 0.f;
        for (int k = 0; k < 200; ++k) {
            float v = bnr(h2b[n * 200 + k], sc[k], sh[k]);
            dr = fmaf(v, wrel[k], dr);
            dt = fmaf(v, wroot[k], dt);
        }
        t2[n] = dr;
        sc2[n] = dt + pb[0];
    }
}

__global__ void k_scatter2(const int* __restrict__ nsrc, const int* __restrict__ ndst,
                           const float* __restrict__ new_ew, const float* __restrict__ t2,
                           float* __restrict__ sc2) {
    int e = blockIdx.x * 256 + threadIdx.x;
    if (e < NE) {
        atomicAdd(&sc2[ndst[e]], new_ew[e] * t2[nsrc[e]]);
    }
}

// ---- pool2 rank+select ----
__global__ void k_rank2(const float* __restrict__ sc2v, const float* __restrict__ h2b,
                        const float* __restrict__ sums2b, const float* __restrict__ g2b,
                        const float* __restrict__ be2b, float* __restrict__ xp2) {
    __shared__ float ss[K1];
    __shared__ float sc[200], sh[200];
    int t = threadIdx.x;
    if (t < 200) {
        float mu = sums2b[t] * (1.f / K1);
        float var = sums2b[200 + t] * (1.f / K1) - mu * mu;
        float s = g2b[t] * rsqrtf(var + EPS);
        sc[t] = s; sh[t] = be2b[t] - mu * s;
    }
    for (int i = t; i < K1; i += 256) ss[i] = sc2v[i];
    __syncthreads();
    int n = blockIdx.x * 256 + t;
    if (n < K1) {
        float s = ss[n];
        int r = 0;
        for (int m = 0; m < K1; ++m) {
            float sm = ss[m];
            r += (sm > s) || (sm == s && m < n);
        }
        if (r < K2) {
            float tn = tanhf(s);
            for (int c = 0; c < 200; ++c)
                xp2[r * 200 + c] = bnr(h2b[n * 200 + c], sc[c], sh[c]) * tn;
        }
    }
}

// ---- global max pool + mlp_third + log_softmax ----
__global__ void k_final(const float* __restrict__ xp2, const float* __restrict__ w3a,
                        const float* __restrict__ b3a, const float* __restrict__ w3b,
                        const float* __restrict__ b3b, float* __restrict__ out) {
    __shared__ float g[200];
    __shared__ float h3[128];
    __shared__ float o[2];
    int t = threadIdx.x;
    if (t < 200) {
        float m = xp2[t];
        for (int n = 1; n < K2; ++n) m = fmaxf(m, xp2[n * 200 + t]);
        g[t] = m;
    }
    __syncthreads();
    if (t < 128) {
        float acc = b3a[t];
        for (int j = 0; j < 200; ++j) acc = fmaf(w3a[t * 200 + j], g[j], acc);
        h3[t] = fmaxf(acc, 0.f);
    }
    __syncthreads();
    if (t < 2) {
        float acc = b3b[t];
        for (int i = 0; i < 128; ++i) acc = fmaf(w3b[t * 128 + i], h3[i], acc);
        o[t] = fmaxf(acc, 0.f);
    }
    __syncthreads();
    if (t == 0) {
        float m = fmaxf(o[0], o[1]);
        float l = m + logf(expf(o[0] - m) + expf(o[1] - m));
        out[0] = o[0] - l;
        out[1] = o[1] - l;
    }
}

extern "C" void kernel_launch(void* const* d_in, const int* in_sizes, int n_in,
                              void* d_out, int out_size, void* d_ws, size_t ws_size,
                              hipStream_t stream) {
    const float* x    = (const float*)d_in[0];
    const int*   ei   = (const int*)d_in[1];
    const float* ea   = (const float*)d_in[2];
    const float* w0   = (const float*)d_in[3];
    const float* b0   = (const float*)d_in[4];
    const float* g0   = (const float*)d_in[5];
    const float* be0  = (const float*)d_in[6];
    const float* w1   = (const float*)d_in[7];
    const float* b1   = (const float*)d_in[8];
    const float* g1   = (const float*)d_in[9];
    const float* be1  = (const float*)d_in[10];
    const float* w2a  = (const float*)d_in[11];
    const float* b2a  = (const float*)d_in[12];
    const float* g2a  = (const float*)d_in[13];
    const float* be2a = (const float*)d_in[14];
    const float* w2b  = (const float*)d_in[15];
    const float* b2b  = (const float*)d_in[16];
    const float* g2b  = (const float*)d_in[17];
    const float* be2b = (const float*)d_in[18];
    const float* w3a  = (const float*)d_in[19];
    const float* b3a  = (const float*)d_in[20];
    const float* w3b  = (const float*)d_in[21];
    const float* b3b  = (const float*)d_in[22];
    const float* p1_wrel  = (const float*)d_in[23];
    const float* p1_wroot = (const float*)d_in[24];
    const float* p1_b     = (const float*)d_in[25];
    const float* p2_wrel  = (const float*)d_in[26];
    const float* p2_wroot = (const float*)d_in[27];
    const float* p2_b     = (const float*)d_in[28];

    float* ws = (float*)d_ws;
    float* h0     = ws;              // 64000
    float* h1     = ws + 64000;      // 64000
    float* sums0  = ws + 128000;     // 128
    float* sums1  = ws + 128128;     // 128
    float* sums2a = ws + 128256;     // 256
    float* sums2b = ws + 128512;     // 400
    float* t1     = ws + 128912;     // 1000
    float* sc1    = ws + 129912;     // 1000
    float* xp1    = ws + 130912;     // 32000
    float* h2a    = ws + 162912;     // 64000
    float* h2b    = ws + 226912;     // 100000
    float* t2     = ws + 326912;     // 500
    float* sc2    = ws + 327412;     // 500
    float* xp2    = ws + 327912;     // 20000
    int*   keep   = (int*)(ws + 347912); // 1000
    int*   nidx   = (int*)(ws + 348912); // 1000
    int*   nsrc   = (int*)(ws + 349912); // 32000
    int*   ndst   = (int*)(ws + 381912); // 32000
    float* new_ew = ws + 413912;         // 32000

    float* out = (float*)d_out;

    k_init<<<1, 256, 0, stream>>>(sums0);
    k_lin0<<<8, 256, 0, stream>>>(x, w0, b0, h0, sums0);
    k_lin1<<<16, 256, 0, stream>>>(h0, w1, b1, g0, be0, sums0, h1, sums1);
    k_score1<<<4, 256, 0, stream>>>(h1, sums1, g1, be1, p1_wrel, p1_wroot, p1_b, t1, sc1);
    k_scatter1<<<125, 256, 0, stream>>>(ei, ea, t1, sc1);
    k_rank1<<<4, 256, 0, stream>>>(sc1, h1, sums1, g1, be1, xp1, keep, nidx);
    k_lin2a_remap<<<133, 256, 0, stream>>>(xp1, w2a, b2a, h2a, sums2a,
                                           ei, ea, keep, nidx, nsrc, ndst, new_ew);
    k_lin2b<<<20, 256, 0, stream>>>(h2a, sums2a, g2a, be2a, w2b, b2b, h2b, sums2b);
    k_score2<<<2, 256, 0, stream>>>(h2b, sums2b, g2b, be2b, p2_wrel, p2_wroot, p2_b, t2, sc2);
    k_scatter2<<<125, 256, 0, stream>>>(nsrc, ndst, new_ew, t2, sc2);
    k_rank2<<<2, 256, 0, stream>>>(sc2, h2b, sums2b, g2b, be2b, xp2);
    k_final<<<1, 256, 0, stream>>>(xp2, w3a, b3a, w3b, b3b, out);
}

// Round 2
// 174.835 us; speedup vs baseline: 2.7520x; 2.7520x over previous
//
#include <hip/hip_runtime.h>
#include <math.h>

#define EPS 1e-5f
#define N0 1000
#define K1 500
#define K2 100
#define NE 32000

__device__ __forceinline__ float bnr(float h, float sc, float sh) {
    float v = fmaf(h, sc, sh);
    return v > 0.f ? v : 0.f;
}

// ---- init: zero the BN sum accumulators (912 floats) ----
__global__ void k_init(float* sums) {
    for (int i = threadIdx.x; i < 912; i += 256) sums[i] = 0.f;
}

// ---- layer0: (1000,3)->(1000,64) raw + channel sums ----
__global__ void k_lin0(const float* __restrict__ x, const float* __restrict__ w0,
                       const float* __restrict__ b0, float* __restrict__ h0,
                       float* __restrict__ sums0) {
    int t = threadIdx.x;
    int c = t & 63, ns = t >> 6;
    int nb = blockIdx.x * 128;
    float wa = w0[c * 3 + 0], wb = w0[c * 3 + 1], wc = w0[c * 3 + 2], bb = b0[c];
    float s = 0.f, q = 0.f;
    for (int j = 0; j < 32; ++j) {
        int n = nb + ns + 4 * j;
        if (n < N0) {
            float h = fmaf(wa, x[n * 3], fmaf(wb, x[n * 3 + 1], fmaf(wc, x[n * 3 + 2], bb)));
            h0[n * 64 + c] = h;
            s += h; q += h * h;
        }
    }
    __shared__ float rs[256], rq[256];
    rs[t] = s; rq[t] = q;
    __syncthreads();
    if (ns == 0) {
        atomicAdd(&sums0[c],      rs[c] + rs[c + 64] + rs[c + 128] + rs[c + 192]);
        atomicAdd(&sums0[64 + c], rq[c] + rq[c + 64] + rq[c + 128] + rq[c + 192]);
    }
}

// ---- layer1: bnrelu(h0) @ w1^T -> h1 raw + sums ----
__global__ void k_lin1(const float* __restrict__ h0, const float* __restrict__ w1,
                       const float* __restrict__ b1v, const float* __restrict__ g0,
                       const float* __restrict__ be0, const float* __restrict__ sums0,
                       float* __restrict__ h1, float* __restrict__ sums1) {
    __shared__ float xs[64][65];
    __shared__ float wsm[64][65];
    __shared__ float sc0[64], sh0[64];
    __shared__ float rs[256], rq[256];
    int t = threadIdx.x;
    int nb = blockIdx.x * 64;
    if (t < 64) {
        float mu = sums0[t] * (1.f / N0);
        float var = sums0[64 + t] * (1.f / N0) - mu * mu;
        float sc = g0[t] * rsqrtf(var + EPS);
        sc0[t] = sc; sh0[t] = be0[t] - mu * sc;
    }
    __syncthreads();
    for (int i = 0; i < 16; ++i) {
        int e = t + i * 256;
        int r = e >> 6, cc = e & 63;
        int n = nb + r;
        xs[r][cc] = (n < N0) ? bnr(h0[n * 64 + cc], sc0[cc], sh0[cc]) : 0.f;
        wsm[r][cc] = w1[e];
    }
    __syncthreads();
    int c = t & 63, ns = t >> 6;
    float s = 0.f, q = 0.f;
    for (int j = 0; j < 16; ++j) {
        int ln = ns + 4 * j;
        int n = nb + ln;
        if (n < N0) {
            float acc = b1v[c];
            #pragma unroll
            for (int k = 0; k < 64; ++k) acc = fmaf(xs[ln][k], wsm[c][k], acc);
            h1[n * 64 + c] = acc;
            s += acc; q += acc * acc;
        }
    }
    rs[t] = s; rq[t] = q;
    __syncthreads();
    if (ns == 0) {
        atomicAdd(&sums1[c],      rs[c] + rs[c + 64] + rs[c + 128] + rs[c + 192]);
        atomicAdd(&sums1[64 + c], rq[c] + rq[c + 64] + rq[c + 128] + rq[c + 192]);
    }
}

// ---- pool1 scores: t1 = x1.w_rel ; sc1 = x1.w_root + b ----
__global__ void k_score1(const float* __restrict__ h1, const float* __restrict__ sums1,
                         const float* __restrict__ g1, const float* __restrict__ be1,
                         const float* __restrict__ wrel, const float* __restrict__ wroot,
                         const float* __restrict__ pb,
                         float* __restrict__ t1, float* __restrict__ sc1) {
    __shared__ float sc[64], sh[64];
    int t = threadIdx.x;
    if (t < 64) {
        float mu = sums1[t] * (1.f / N0);
        float var = sums1[64 + t] * (1.f / N0) - mu * mu;
        float s = g1[t] * rsqrtf(var + EPS);
        sc[t] = s; sh[t] = be1[t] - mu * s;
    }
    __syncthreads();
    int n = blockIdx.x * 256 + t;
    if (n < N0) {
        float dr = 0.f, dt = 0.f;
        for (int k = 0; k < 64; ++k) {
            float v = bnr(h1[n * 64 + k], sc[k], sh[k]);
            dr = fmaf(v, wrel[k], dr);
            dt = fmaf(v, wroot[k], dt);
        }
        t1[n] = dr;
        sc1[n] = dt + pb[0];
    }
}

// ---- LDS-aggregated scatter: sc1[dst] += ew * t1[src] ----
__global__ void k_scatter1(const int* __restrict__ ei, const float* __restrict__ ea,
                           const float* __restrict__ t1, float* __restrict__ sc1) {
    __shared__ float acc[N0];
    int t = threadIdx.x;
    for (int i = t; i < N0; i += 256) acc[i] = 0.f;
    __syncthreads();
    for (int e = blockIdx.x * 256 + t; e < NE; e += gridDim.x * 256) {
        float w = ea[e];
        if (w != 0.f) atomicAdd(&acc[ei[NE + e]], w * t1[ei[e]]);
    }
    __syncthreads();
    for (int i = t; i < N0; i += 256) {
        float v = acc[i];
        if (v != 0.f) atomicAdd(&sc1[i], v);
    }
}

// ---- pool1 rank+select: xp1[rank] = x1[n]*tanh(s) ----
__global__ void k_rank1(const float* __restrict__ sc1, const float* __restrict__ h1,
                        const float* __restrict__ sums1, const float* __restrict__ g1,
                        const float* __restrict__ be1,
                        float* __restrict__ xp1, int* __restrict__ keep, int* __restrict__ nidx) {
    __shared__ float ss[N0];
    __shared__ float sc[64], sh[64];
    int t = threadIdx.x;
    if (t < 64) {
        float mu = sums1[t] * (1.f / N0);
        float var = sums1[64 + t] * (1.f / N0) - mu * mu;
        float s = g1[t] * rsqrtf(var + EPS);
        sc[t] = s; sh[t] = be1[t] - mu * s;
    }
    for (int i = t; i < N0; i += 256) ss[i] = sc1[i];
    __syncthreads();
    int n = blockIdx.x * 256 + t;
    if (n < N0) {
        float s = ss[n];
        int r = 0;
        for (int m = 0; m < N0; ++m) {
            float sm = ss[m];
            r += (sm > s) || (sm == s && m < n);
        }
        keep[n] = (r < K1) ? 1 : 0;
        nidx[n] = (r < K1) ? r : 0;
        if (r < K1) {
            float tn = tanhf(s);
            for (int c = 0; c < 64; ++c)
                xp1[r * 64 + c] = bnr(h1[n * 64 + c], sc[c], sh[c]) * tn;
        }
    }
}

// ---- fused: layer2a matmul (blocks 0..7) + edge remap (blocks 8..132) ----
__global__ void k_lin2a_remap(const float* __restrict__ xp1, const float* __restrict__ w2a,
                              const float* __restrict__ b2a, float* __restrict__ h2a,
                              float* __restrict__ sums2a,
                              const int* __restrict__ ei, const float* __restrict__ ea,
                              const int* __restrict__ keep, const int* __restrict__ nidx,
                              int* __restrict__ nsrc, int* __restrict__ ndst,
                              float* __restrict__ new_ew) {
    __shared__ float xs[64][65];
    __shared__ float wsm[128][65];
    __shared__ float rs[256], rq[256];
    int b = blockIdx.x;
    int t = threadIdx.x;
    if (b < 8) {
        int nb = b * 64;
        for (int i = 0; i < 16; ++i) {
            int e = t + i * 256;
            int r = e >> 6, cc = e & 63;
            int n = nb + r;
            xs[r][cc] = (n < K1) ? xp1[n * 64 + cc] : 0.f;
        }
        for (int i = 0; i < 32; ++i) {
            int e = t + i * 256;
            wsm[e >> 6][e & 63] = w2a[e];
        }
        __syncthreads();
        int c = t & 127, ns = t >> 7;
        float s = 0.f, q = 0.f;
        for (int j = 0; j < 32; ++j) {
            int ln = ns + 2 * j;
            int n = nb + ln;
            if (n < K1) {
                float acc = b2a[c];
                #pragma unroll
                for (int k = 0; k < 64; ++k) acc = fmaf(xs[ln][k], wsm[c][k], acc);
                h2a[n * 128 + c] = acc;
                s += acc; q += acc * acc;
            }
        }
        rs[t] = s; rq[t] = q;
        __syncthreads();
        if (ns == 0) {
            atomicAdd(&sums2a[c],       rs[c] + rs[c + 128]);
            atomicAdd(&sums2a[128 + c], rq[c] + rq[c + 128]);
        }
    } else {
        int e = (b - 8) * 256 + t;
        if (e < NE) {
            int s = ei[e], d = ei[NE + e];
            bool v = keep[s] && keep[d];
            nsrc[e] = v ? nidx[s] : 0;
            ndst[e] = v ? nidx[d] : 0;
            new_ew[e] = v ? ea[e] : 0.f;
        }
    }
}

// ---- layer2b: bnrelu(h2a) @ w2b^T -> h2b raw + sums. 25 nodes/block, thread=out channel ----
__global__ void k_lin2b(const float* __restrict__ h2a, const float* __restrict__ sums2a,
                        const float* __restrict__ g2a, const float* __restrict__ be2a,
                        const float* __restrict__ w2b, const float* __restrict__ b2b,
                        float* __restrict__ h2b, float* __restrict__ sums2b) {
    __shared__ float xs[25][130];
    __shared__ float sc[128], sh[128];
    int t = threadIdx.x;
    if (t < 128) {
        float mu = sums2a[t] * (1.f / K1);
        float var = sums2a[128 + t] * (1.f / K1) - mu * mu;
        float s = g2a[t] * rsqrtf(var + EPS);
        sc[t] = s; sh[t] = be2a[t] - mu * s;
    }
    __syncthreads();
    int nb = blockIdx.x * 25;
    for (int i = t; i < 25 * 128; i += 256) {
        int r = i >> 7, cc = i & 127;
        int n = nb + r;
        xs[r][cc] = (n < K1) ? bnr(h2a[n * 128 + cc], sc[cc], sh[cc]) : 0.f;
    }
    __syncthreads();
    if (t < 200) {
        int c = t;
        float acc[25];
        float bb = b2b[c];
        #pragma unroll
        for (int r = 0; r < 25; ++r) acc[r] = bb;
        for (int k = 0; k < 128; ++k) {
            float wv = w2b[c * 128 + k];
            #pragma unroll
            for (int r = 0; r < 25; ++r) acc[r] = fmaf(xs[r][k], wv, acc[r]);
        }
        float s = 0.f, q = 0.f;
        for (int r = 0; r < 25; ++r) {
            int n = nb + r;
            if (n < K1) {
                h2b[n * 200 + c] = acc[r];
                s += acc[r]; q += acc[r] * acc[r];
            }
        }
        atomicAdd(&sums2b[c], s);
        atomicAdd(&sums2b[200 + c], q);
    }
}

// ---- pool2 scores ----
__global__ void k_score2(const float* __restrict__ h2b, const float* __restrict__ sums2b,
                         const float* __restrict__ g2b, const float* __restrict__ be2b,
                         const float* __restrict__ wrel, const float* __restrict__ wroot,
                         const float* __restrict__ pb,
                         float* __restrict__ t2, float* __restrict__ sc2) {
    __shared__ float sc[200], sh[200];
    int t = threadIdx.x;
    if (t < 200) {
        float mu = sums2b[t] * (1.f / K1);
        float var = sums2b[200 + t] * (1.f / K1) - mu * mu;
        float s = g2b[t] * rsqrtf(var + EPS);
        sc[t] = s; sh[t] = be2b[t] - mu * s;
    }
    __syncthreads();
    int n = blockIdx.x * 256 + t;
    if (n < K1) {
        float dr = 0.f, dt = 0.f;
        for (int k = 0; k < 200; ++k) {
            float v = bnr(h2b[n * 200 + k], sc[k], sh[k]);
            dr = fmaf(v, wrel[k], dr);
            dt = fmaf(v, wroot[k], dt);
        }
        t2[n] = dr;
        sc2[n] = dt + pb[0];
    }
}

// ---- LDS-aggregated scatter: sc2[dst] += ew * t2[src], skip dead edges ----
__global__ void k_scatter2(const int* __restrict__ nsrc, const int* __restrict__ ndst,
                           const float* __restrict__ new_ew, const float* __restrict__ t2,
                           float* __restrict__ sc2) {
    __shared__ float acc[K1];
    int t = threadIdx.x;
    for (int i = t; i < K1; i += 256) acc[i] = 0.f;
    __syncthreads();
    for (int e = blockIdx.x * 256 + t; e < NE; e += gridDim.x * 256) {
        float w = new_ew[e];
        if (w != 0.f) atomicAdd(&acc[ndst[e]], w * t2[nsrc[e]]);
    }
    __syncthreads();
    for (int i = t; i < K1; i += 256) {
        float v = acc[i];
        if (v != 0.f) atomicAdd(&sc2[i], v);
    }
}

// ---- pool2 rank+select ----
__global__ void k_rank2(const float* __restrict__ sc2v, const float* __restrict__ h2b,
                        const float* __restrict__ sums2b, const float* __restrict__ g2b,
                        const float* __restrict__ be2b, float* __restrict__ xp2) {
    __shared__ float ss[K1];
    __shared__ float sc[200], sh[200];
    int t = threadIdx.x;
    if (t < 200) {
        float mu = sums2b[t] * (1.f / K1);
        float var = sums2b[200 + t] * (1.f / K1) - mu * mu;
        float s = g2b[t] * rsqrtf(var + EPS);
        sc[t] = s; sh[t] = be2b[t] - mu * s;
    }
    for (int i = t; i < K1; i += 256) ss[i] = sc2v[i];
    __syncthreads();
    int n = blockIdx.x * 256 + t;
    if (n < K1) {
        float s = ss[n];
        int r = 0;
        for (int m = 0; m < K1; ++m) {
            float sm = ss[m];
            r += (sm > s) || (sm == s && m < n);
        }
        if (r < K2) {
            float tn = tanhf(s);
            for (int c = 0; c < 200; ++c)
                xp2[r * 200 + c] = bnr(h2b[n * 200 + c], sc[c], sh[c]) * tn;
        }
    }
}

// ---- global max pool + mlp_third + log_softmax ----
__global__ void k_final(const float* __restrict__ xp2, const float* __restrict__ w3a,
                        const float* __restrict__ b3a, const float* __restrict__ w3b,
                        const float* __restrict__ b3b, float* __restrict__ out) {
    __shared__ float g[200];
    __shared__ float h3[128];
    __shared__ float o[2];
    int t = threadIdx.x;
    if (t < 200) {
        float m = xp2[t];
        for (int n = 1; n < K2; ++n) m = fmaxf(m, xp2[n * 200 + t]);
        g[t] = m;
    }
    __syncthreads();
    if (t < 128) {
        float acc = b3a[t];
        for (int j = 0; j < 200; ++j) acc = fmaf(w3a[t * 200 + j], g[j], acc);
        h3[t] = fmaxf(acc, 0.f);
    }
    __syncthreads();
    if (t < 2) {
        float acc = b3b[t];
        for (int i = 0; i < 128; ++i) acc = fmaf(w3b[t * 128 + i], h3[i], acc);
        o[t] = fmaxf(acc, 0.f);
    }
    __syncthreads();
    if (t == 0) {
        float m = fmaxf(o[0], o[1]);
        float l = m + logf(expf(o[0] - m) + expf(o[1] - m));
        out[0] = o[0] - l;
        out[1] = o[1] - l;
    }
}

extern "C" void kernel_launch(void* const* d_in, const int* in_sizes, int n_in,
                              void* d_out, int out_size, void* d_ws, size_t ws_size,
                              hipStream_t stream) {
    const float* x    = (const float*)d_in[0];
    const int*   ei   = (const int*)d_in[1];
    const float* ea   = (const float*)d_in[2];
    const float* w0   = (const float*)d_in[3];
    const float* b0   = (const float*)d_in[4];
    const float* g0   = (const float*)d_in[5];
    const float* be0  = (const float*)d_in[6];
    const float* w1   = (const float*)d_in[7];
    const float* b1   = (const float*)d_in[8];
    const float* g1   = (const float*)d_in[9];
    const float* be1  = (const float*)d_in[10];
    const float* w2a  = (const float*)d_in[11];
    const float* b2a  = (const float*)d_in[12];
    const float* g2a  = (const float*)d_in[13];
    const float* be2a = (const float*)d_in[14];
    const float* w2b  = (const float*)d_in[15];
    const float* b2b  = (const float*)d_in[16];
    const float* g2b  = (const float*)d_in[17];
    const float* be2b = (const float*)d_in[18];
    const float* w3a  = (const float*)d_in[19];
    const float* b3a  = (const float*)d_in[20];
    const float* w3b  = (const float*)d_in[21];
    const float* b3b  = (const float*)d_in[22];
    const float* p1_wrel  = (const float*)d_in[23];
    const float* p1_wroot = (const float*)d_in[24];
    const float* p1_b     = (const float*)d_in[25];
    const float* p2_wrel  = (const float*)d_in[26];
    const float* p2_wroot = (const float*)d_in[27];
    const float* p2_b     = (const float*)d_in[28];

    float* ws = (float*)d_ws;
    float* h0     = ws;              // 64000
    float* h1     = ws + 64000;      // 64000
    float* sums0  = ws + 128000;     // 128
    float* sums1  = ws + 128128;     // 128
    float* sums2a = ws + 128256;     // 256
    float* sums2b = ws + 128512;     // 400
    float* t1     = ws + 128912;     // 1000
    float* sc1    = ws + 129912;     // 1000
    float* xp1    = ws + 130912;     // 32000
    float* h2a    = ws + 162912;     // 64000
    float* h2b    = ws + 226912;     // 100000
    float* t2     = ws + 326912;     // 500
    float* sc2    = ws + 327412;     // 500
    float* xp2    = ws + 327912;     // 20000
    int*   keep   = (int*)(ws + 347912); // 1000
    int*   nidx   = (int*)(ws + 348912); // 1000
    int*   nsrc   = (int*)(ws + 349912); // 32000
    int*   ndst   = (int*)(ws + 381912); // 32000
    float* new_ew = ws + 413912;         // 32000

    float* out = (float*)d_out;

    k_init<<<1, 256, 0, stream>>>(sums0);
    k_lin0<<<8, 256, 0, stream>>>(x, w0, b0, h0, sums0);
    k_lin1<<<16, 256, 0, stream>>>(h0, w1, b1, g0, be0, sums0, h1, sums1);
    k_score1<<<4, 256, 0, stream>>>(h1, sums1, g1, be1, p1_wrel, p1_wroot, p1_b, t1, sc1);
    k_scatter1<<<16, 256, 0, stream>>>(ei, ea, t1, sc1);
    k_rank1<<<4, 256, 0, stream>>>(sc1, h1, sums1, g1, be1, xp1, keep, nidx);
    k_lin2a_remap<<<133, 256, 0, stream>>>(xp1, w2a, b2a, h2a, sums2a,
                                           ei, ea, keep, nidx, nsrc, ndst, new_ew);
    k_lin2b<<<20, 256, 0, stream>>>(h2a, sums2a, g2a, be2a, w2b, b2b, h2b, sums2b);
    k_score2<<<2, 256, 0, stream>>>(h2b, sums2b, g2b, be2b, p2_wrel, p2_wroot, p2_b, t2, sc2);
    k_scatter2<<<16, 256, 0, stream>>>(nsrc, ndst, new_ew, t2, sc2);
    k_rank2<<<2, 256, 0, stream>>>(sc2, h2b, sums2b, g2b, be2b, xp2);
    k_final<<<1, 256, 0, stream>>>(xp2, w3a, b3a, w3b, b3b, out);
}

// Round 3
// 130.297 us; speedup vs baseline: 3.6926x; 1.3418x over previous
//
#include <hip/hip_runtime.h>
#include <math.h>

#define EPS 1e-5f
#define N0 1000
#define K1 500
#define K2 100
#define NE 32000

__device__ __forceinline__ float bnr(float h, float sc, float sh) {
    float v = fmaf(h, sc, sh);
    return v > 0.f ? v : 0.f;
}

// ---- layer0: (1000,3)->(1000,64) raw + per-block channel partial sums ----
__global__ void k_lin0(const float* __restrict__ x, const float* __restrict__ w0,
                       const float* __restrict__ b0, float* __restrict__ h0,
                       float* __restrict__ psum0) {
    int t = threadIdx.x;
    int c = t & 63, ns = t >> 6;
    int nb = blockIdx.x * 128;
    float wa = w0[c * 3 + 0], wb = w0[c * 3 + 1], wc = w0[c * 3 + 2], bb = b0[c];
    float s = 0.f, q = 0.f;
    for (int j = 0; j < 32; ++j) {
        int n = nb + ns + 4 * j;
        if (n < N0) {
            float h = fmaf(wa, x[n * 3], fmaf(wb, x[n * 3 + 1], fmaf(wc, x[n * 3 + 2], bb)));
            h0[n * 64 + c] = h;
            s += h; q += h * h;
        }
    }
    __shared__ float rs[256], rq[256];
    rs[t] = s; rq[t] = q;
    __syncthreads();
    if (ns == 0) {
        psum0[blockIdx.x * 128 + c]      = rs[c] + rs[c + 64] + rs[c + 128] + rs[c + 192];
        psum0[blockIdx.x * 128 + 64 + c] = rq[c] + rq[c + 64] + rq[c + 128] + rq[c + 192];
    }
}

// ---- layer1: bnrelu(h0) @ w1^T -> h1 raw + partial sums ----
__global__ void k_lin1(const float* __restrict__ h0, const float* __restrict__ w1,
                       const float* __restrict__ b1v, const float* __restrict__ g0,
                       const float* __restrict__ be0, const float* __restrict__ psum0,
                       float* __restrict__ h1, float* __restrict__ psum1) {
    __shared__ float xs[64][65];
    __shared__ float wsm[64][65];
    __shared__ float sc0[64], sh0[64];
    __shared__ float rs[256], rq[256];
    int t = threadIdx.x;
    int nb = blockIdx.x * 64;
    if (t < 64) {
        float s = 0.f, q = 0.f;
        for (int i = 0; i < 8; ++i) { s += psum0[i * 128 + t]; q += psum0[i * 128 + 64 + t]; }
        float mu = s * (1.f / N0);
        float var = q * (1.f / N0) - mu * mu;
        float sc = g0[t] * rsqrtf(var + EPS);
        sc0[t] = sc; sh0[t] = be0[t] - mu * sc;
    }
    __syncthreads();
    for (int i = 0; i < 16; ++i) {
        int e = t + i * 256;
        int r = e >> 6, cc = e & 63;
        int n = nb + r;
        xs[r][cc] = (n < N0) ? bnr(h0[n * 64 + cc], sc0[cc], sh0[cc]) : 0.f;
        wsm[r][cc] = w1[e];
    }
    __syncthreads();
    int c = t & 63, ns = t >> 6;
    float s = 0.f, q = 0.f;
    for (int j = 0; j < 16; ++j) {
        int ln = ns + 4 * j;
        int n = nb + ln;
        if (n < N0) {
            float acc = b1v[c];
            #pragma unroll
            for (int k = 0; k < 64; ++k) acc = fmaf(xs[ln][k], wsm[c][k], acc);
            h1[n * 64 + c] = acc;
            s += acc; q += acc * acc;
        }
    }
    rs[t] = s; rq[t] = q;
    __syncthreads();
    if (ns == 0) {
        psum1[blockIdx.x * 128 + c]      = rs[c] + rs[c + 64] + rs[c + 128] + rs[c + 192];
        psum1[blockIdx.x * 128 + 64 + c] = rq[c] + rq[c + 64] + rq[c + 128] + rq[c + 192];
    }
}

// ---- pool1 scores, wave-per-node: t1 = x1.w_rel ; sc1 = x1.w_root + b ----
__global__ void k_score1(const float* __restrict__ h1, const float* __restrict__ psum1,
                         const float* __restrict__ g1, const float* __restrict__ be1,
                         const float* __restrict__ wrel, const float* __restrict__ wroot,
                         const float* __restrict__ pb,
                         float* __restrict__ t1, float* __restrict__ sc1) {
    __shared__ float sc[64], sh[64];
    int t = threadIdx.x;
    if (t < 64) {
        float s = 0.f, q = 0.f;
        for (int i = 0; i < 16; ++i) { s += psum1[i * 128 + t]; q += psum1[i * 128 + 64 + t]; }
        float mu = s * (1.f / N0);
        float var = q * (1.f / N0) - mu * mu;
        float sv = g1[t] * rsqrtf(var + EPS);
        sc[t] = sv; sh[t] = be1[t] - mu * sv;
    }
    __syncthreads();
    int lane = t & 63, w = t >> 6;
    int n = blockIdx.x * 4 + w;
    if (n < N0) {
        float v = bnr(h1[n * 64 + lane], sc[lane], sh[lane]);
        float dr = v * wrel[lane], dt = v * wroot[lane];
        #pragma unroll
        for (int m = 32; m >= 1; m >>= 1) {
            dr += __shfl_xor(dr, m, 64);
            dt += __shfl_xor(dt, m, 64);
        }
        if (lane == 0) { t1[n] = dr; sc1[n] = dt + pb[0]; }
    }
}

// ---- LDS-aggregated scatter: sc1[dst] += ew * t1[src] ----
__global__ void k_scatter1(const int* __restrict__ ei, const float* __restrict__ ea,
                           const float* __restrict__ t1, float* __restrict__ sc1) {
    __shared__ float acc[N0];
    int t = threadIdx.x;
    for (int i = t; i < N0; i += 256) acc[i] = 0.f;
    __syncthreads();
    for (int e = blockIdx.x * 256 + t; e < NE; e += gridDim.x * 256) {
        float w = ea[e];
        if (w != 0.f) atomicAdd(&acc[ei[NE + e]], w * t1[ei[e]]);
    }
    __syncthreads();
    for (int i = t; i < N0; i += 256) {
        float v = acc[i];
        if (v != 0.f) atomicAdd(&sc1[i], v);
    }
}

// ---- pool1 rank+select, wave-per-node: xp1[rank] = x1[n]*tanh(s) ----
__global__ void k_rank1(const float* __restrict__ sc1, const float* __restrict__ h1,
                        const float* __restrict__ psum1, const float* __restrict__ g1,
                        const float* __restrict__ be1,
                        float* __restrict__ xp1, int* __restrict__ keep, int* __restrict__ nidx) {
    __shared__ float ss[N0];
    __shared__ float sc[64], sh[64];
    int t = threadIdx.x;
    if (t < 64) {
        float s = 0.f, q = 0.f;
        for (int i = 0; i < 16; ++i) { s += psum1[i * 128 + t]; q += psum1[i * 128 + 64 + t]; }
        float mu = s * (1.f / N0);
        float var = q * (1.f / N0) - mu * mu;
        float sv = g1[t] * rsqrtf(var + EPS);
        sc[t] = sv; sh[t] = be1[t] - mu * sv;
    }
    for (int i = t; i < N0; i += 256) ss[i] = sc1[i];
    __syncthreads();
    int lane = t & 63, w = t >> 6;
    int n = blockIdx.x * 4 + w;
    if (n < N0) {
        float s = ss[n];
        int r = 0;
        for (int m = lane; m < N0; m += 64) {
            float sm = ss[m];
            r += (sm > s) || (sm == s && m < n);
        }
        #pragma unroll
        for (int msk = 32; msk >= 1; msk >>= 1) r += __shfl_xor(r, msk, 64);
        if (lane == 0) { keep[n] = (r < K1) ? 1 : 0; nidx[n] = (r < K1) ? r : 0; }
        if (r < K1) {
            float tn = tanhf(s);
            xp1[r * 64 + lane] = bnr(h1[n * 64 + lane], sc[lane], sh[lane]) * tn;
        }
    }
}

// ---- fused: layer2a matmul (blocks 0..7) + edge remap (blocks 8..132) ----
__global__ void k_lin2a_remap(const float* __restrict__ xp1, const float* __restrict__ w2a,
                              const float* __restrict__ b2a, float* __restrict__ h2a,
                              float* __restrict__ psum2a,
                              const int* __restrict__ ei, const float* __restrict__ ea,
                              const int* __restrict__ keep, const int* __restrict__ nidx,
                              int* __restrict__ nsrc, int* __restrict__ ndst,
                              float* __restrict__ new_ew) {
    __shared__ float xs[64][65];
    __shared__ float wsm[128][65];
    __shared__ float rs[256], rq[256];
    int b = blockIdx.x;
    int t = threadIdx.x;
    if (b < 8) {
        int nb = b * 64;
        for (int i = 0; i < 16; ++i) {
            int e = t + i * 256;
            int r = e >> 6, cc = e & 63;
            int n = nb + r;
            xs[r][cc] = (n < K1) ? xp1[n * 64 + cc] : 0.f;
        }
        for (int i = 0; i < 32; ++i) {
            int e = t + i * 256;
            wsm[e >> 6][e & 63] = w2a[e];
        }
        __syncthreads();
        int c = t & 127, ns = t >> 7;
        float s = 0.f, q = 0.f;
        for (int j = 0; j < 32; ++j) {
            int ln = ns + 2 * j;
            int n = nb + ln;
            if (n < K1) {
                float acc = b2a[c];
                #pragma unroll
                for (int k = 0; k < 64; ++k) acc = fmaf(xs[ln][k], wsm[c][k], acc);
                h2a[n * 128 + c] = acc;
                s += acc; q += acc * acc;
            }
        }
        rs[t] = s; rq[t] = q;
        __syncthreads();
        if (ns == 0) {
            psum2a[b * 256 + c]       = rs[c] + rs[c + 128];
            psum2a[b * 256 + 128 + c] = rq[c] + rq[c + 128];
        }
    } else {
        int e = (b - 8) * 256 + t;
        if (e < NE) {
            int s = ei[e], d = ei[NE + e];
            bool v = keep[s] && keep[d];
            nsrc[e] = v ? nidx[s] : 0;
            ndst[e] = v ? nidx[d] : 0;
            new_ew[e] = v ? ea[e] : 0.f;
        }
    }
}

// ---- layer2b: bnrelu(h2a) @ w2b^T, k-tiled LDS staging of w2b ----
__global__ void k_lin2b(const float* __restrict__ h2a, const float* __restrict__ psum2a,
                        const float* __restrict__ g2a, const float* __restrict__ be2a,
                        const float* __restrict__ w2b, const float* __restrict__ b2b,
                        float* __restrict__ h2b, float* __restrict__ psum2b) {
    __shared__ float wsm[200][33];
    __shared__ float xs[25][33];
    __shared__ float sc[128], sh[128];
    int t = threadIdx.x;
    if (t < 128) {
        float s = 0.f, q = 0.f;
        for (int i = 0; i < 8; ++i) { s += psum2a[i * 256 + t]; q += psum2a[i * 256 + 128 + t]; }
        float mu = s * (1.f / K1);
        float var = q * (1.f / K1) - mu * mu;
        float sv = g2a[t] * rsqrtf(var + EPS);
        sc[t] = sv; sh[t] = be2a[t] - mu * sv;
    }
    __syncthreads();
    int nb = blockIdx.x * 25;
    float acc[25];
    if (t < 200) {
        float bb = b2b[t];
        #pragma unroll
        for (int r = 0; r < 25; ++r) acc[r] = bb;
    }
    for (int kt = 0; kt < 4; ++kt) {
        int k0 = kt * 32;
        __syncthreads();
        for (int e = t; e < 200 * 32; e += 256) {
            int r = e >> 5, k = e & 31;
            wsm[r][k] = w2b[r * 128 + k0 + k];
        }
        for (int e = t; e < 25 * 32; e += 256) {
            int r = e >> 5, k = e & 31;
            int n = nb + r;
            xs[r][k] = bnr(h2a[n * 128 + k0 + k], sc[k0 + k], sh[k0 + k]);
        }
        __syncthreads();
        if (t < 200) {
            for (int k = 0; k < 32; ++k) {
                float wv = wsm[t][k];
                #pragma unroll
                for (int r = 0; r < 25; ++r) acc[r] = fmaf(xs[r][k], wv, acc[r]);
            }
        }
    }
    if (t < 200) {
        float s = 0.f, q = 0.f;
        #pragma unroll
        for (int r = 0; r < 25; ++r) {
            int n = nb + r;
            h2b[n * 200 + t] = acc[r];
            s += acc[r]; q += acc[r] * acc[r];
        }
        psum2b[blockIdx.x * 400 + t]       = s;
        psum2b[blockIdx.x * 400 + 200 + t] = q;
    }
}

// ---- pool2 scores, wave-per-node ----
__global__ void k_score2(const float* __restrict__ h2b, const float* __restrict__ psum2b,
                         const float* __restrict__ g2b, const float* __restrict__ be2b,
                         const float* __restrict__ wrel, const float* __restrict__ wroot,
                         const float* __restrict__ pb,
                         float* __restrict__ t2, float* __restrict__ sc2) {
    __shared__ float sc[200], sh[200];
    int t = threadIdx.x;
    if (t < 200) {
        float s = 0.f, q = 0.f;
        for (int i = 0; i < 20; ++i) { s += psum2b[i * 400 + t]; q += psum2b[i * 400 + 200 + t]; }
        float mu = s * (1.f / K1);
        float var = q * (1.f / K1) - mu * mu;
        float sv = g2b[t] * rsqrtf(var + EPS);
        sc[t] = sv; sh[t] = be2b[t] - mu * sv;
    }
    __syncthreads();
    int lane = t & 63, w = t >> 6;
    int n = blockIdx.x * 4 + w;
    if (n < K1) {
        float dr = 0.f, dt = 0.f;
        #pragma unroll
        for (int j = 0; j < 4; ++j) {
            int ch = lane + 64 * j;
            if (ch < 200) {
                float v = bnr(h2b[n * 200 + ch], sc[ch], sh[ch]);
                dr = fmaf(v, wrel[ch], dr);
                dt = fmaf(v, wroot[ch], dt);
            }
        }
        #pragma unroll
        for (int m = 32; m >= 1; m >>= 1) {
            dr += __shfl_xor(dr, m, 64);
            dt += __shfl_xor(dt, m, 64);
        }
        if (lane == 0) { t2[n] = dr; sc2[n] = dt + pb[0]; }
    }
}

// ---- LDS-aggregated scatter: sc2[dst] += ew * t2[src], skip dead edges ----
__global__ void k_scatter2(const int* __restrict__ nsrc, const int* __restrict__ ndst,
                           const float* __restrict__ new_ew, const float* __restrict__ t2,
                           float* __restrict__ sc2) {
    __shared__ float acc[K1];
    int t = threadIdx.x;
    for (int i = t; i < K1; i += 256) acc[i] = 0.f;
    __syncthreads();
    for (int e = blockIdx.x * 256 + t; e < NE; e += gridDim.x * 256) {
        float w = new_ew[e];
        if (w != 0.f) atomicAdd(&acc[ndst[e]], w * t2[nsrc[e]]);
    }
    __syncthreads();
    for (int i = t; i < K1; i += 256) {
        float v = acc[i];
        if (v != 0.f) atomicAdd(&sc2[i], v);
    }
}

// ---- pool2 rank+select, wave-per-node ----
__global__ void k_rank2(const float* __restrict__ sc2v, const float* __restrict__ h2b,
                        const float* __restrict__ psum2b, const float* __restrict__ g2b,
                        const float* __restrict__ be2b, float* __restrict__ xp2) {
    __shared__ float ss[K1];
    __shared__ float sc[200], sh[200];
    int t = threadIdx.x;
    if (t < 200) {
        float s = 0.f, q = 0.f;
        for (int i = 0; i < 20; ++i) { s += psum2b[i * 400 + t]; q += psum2b[i * 400 + 200 + t]; }
        float mu = s * (1.f / K1);
        float var = q * (1.f / K1) - mu * mu;
        float sv = g2b[t] * rsqrtf(var + EPS);
        sc[t] = sv; sh[t] = be2b[t] - mu * sv;
    }
    for (int i = t; i < K1; i += 256) ss[i] = sc2v[i];
    __syncthreads();
    int lane = t & 63, w = t >> 6;
    int n = blockIdx.x * 4 + w;
    if (n < K1) {
        float s = ss[n];
        int r = 0;
        for (int m = lane; m < K1; m += 64) {
            float sm = ss[m];
            r += (sm > s) || (sm == s && m < n);
        }
        #pragma unroll
        for (int msk = 32; msk >= 1; msk >>= 1) r += __shfl_xor(r, msk, 64);
        if (r < K2) {
            float tn = tanhf(s);
            #pragma unroll
            for (int j = 0; j < 4; ++j) {
                int ch = lane + 64 * j;
                if (ch < 200)
                    xp2[r * 200 + ch] = bnr(h2b[n * 200 + ch], sc[ch], sh[ch]) * tn;
            }
        }
    }
}

// ---- global max pool + mlp_third + log_softmax (LDS-staged w3a) ----
__global__ void k_final(const float* __restrict__ xp2, const float* __restrict__ w3a,
                        const float* __restrict__ b3a, const float* __restrict__ w3b,
                        const float* __restrict__ b3b, float* __restrict__ out) {
    __shared__ float g[200];
    __shared__ float buf[64][201];
    __shared__ float part[256];
    __shared__ float h3[128];
    __shared__ float o[2];
    int t = threadIdx.x;
    if (t < 200) {
        float m = -1e30f;
        for (int n = 0; n < K2; ++n) m = fmaxf(m, xp2[n * 200 + t]);
        g[t] = m;
    }
    __syncthreads();
    int lane = t & 63, q = t >> 6;
    for (int chunk = 0; chunk < 2; ++chunk) {
        int r0 = chunk * 64;
        __syncthreads();
        for (int e = t; e < 64 * 200; e += 256) {
            int r = e / 200, j = e - r * 200;
            buf[r][j] = w3a[r0 * 200 + e];
        }
        __syncthreads();
        float p = 0.f;
        for (int j = q * 50; j < q * 50 + 50; ++j) p = fmaf(buf[lane][j], g[j], p);
        part[t] = p;
        __syncthreads();
        if (t < 64) {
            float a = part[t] + part[t + 64] + part[t + 128] + part[t + 192] + b3a[r0 + t];
            h3[r0 + t] = fmaxf(a, 0.f);
        }
    }
    __syncthreads();
    if (t < 128) {
        int ow = t >> 6;
        float p = w3b[ow * 128 + lane] * h3[lane] + w3b[ow * 128 + 64 + lane] * h3[64 + lane];
        #pragma unroll
        for (int m = 32; m >= 1; m >>= 1) p += __shfl_xor(p, m, 64);
        if (lane == 0) o[ow] = fmaxf(p + b3b[ow], 0.f);
    }
    __syncthreads();
    if (t == 0) {
        float m = fmaxf(o[0], o[1]);
        float l = m + logf(expf(o[0] - m) + expf(o[1] - m));
        out[0] = o[0] - l;
        out[1] = o[1] - l;
    }
}

extern "C" void kernel_launch(void* const* d_in, const int* in_sizes, int n_in,
                              void* d_out, int out_size, void* d_ws, size_t ws_size,
                              hipStream_t stream) {
    const float* x    = (const float*)d_in[0];
    const int*   ei   = (const int*)d_in[1];
    const float* ea   = (const float*)d_in[2];
    const float* w0   = (const float*)d_in[3];
    const float* b0   = (const float*)d_in[4];
    const float* g0   = (const float*)d_in[5];
    const float* be0  = (const float*)d_in[6];
    const float* w1   = (const float*)d_in[7];
    const float* b1   = (const float*)d_in[8];
    const float* g1   = (const float*)d_in[9];
    const float* be1  = (const float*)d_in[10];
    const float* w2a  = (const float*)d_in[11];
    const float* b2a  = (const float*)d_in[12];
    const float* g2a  = (const float*)d_in[13];
    const float* be2a = (const float*)d_in[14];
    const float* w2b  = (const float*)d_in[15];
    const float* b2b  = (const float*)d_in[16];
    const float* g2b  = (const float*)d_in[17];
    const float* be2b = (const float*)d_in[18];
    const float* w3a  = (const float*)d_in[19];
    const float* b3a  = (const float*)d_in[20];
    const float* w3b  = (const float*)d_in[21];
    const float* b3b  = (const float*)d_in[22];
    const float* p1_wrel  = (const float*)d_in[23];
    const float* p1_wroot = (const float*)d_in[24];
    const float* p1_b     = (const float*)d_in[25];
    const float* p2_wrel  = (const float*)d_in[26];
    const float* p2_wroot = (const float*)d_in[27];
    const float* p2_b     = (const float*)d_in[28];

    float* ws = (float*)d_ws;
    float* h0     = ws;                  // 64000
    float* h1     = ws + 64000;          // 64000
    float* psum0  = ws + 128000;         // 1024  (8 x 128)
    float* psum1  = ws + 129024;         // 2048  (16 x 128)
    float* psum2a = ws + 131072;         // 2048  (8 x 256)
    float* psum2b = ws + 133120;         // 8000  (20 x 400)
    float* t1     = ws + 141120;         // 1000
    float* sc1    = ws + 142120;         // 1000
    float* xp1    = ws + 143120;         // 32000
    float* h2a    = ws + 175120;         // 64000
    float* h2b    = ws + 239120;         // 100000
    float* t2     = ws + 339120;         // 500
    float* sc2    = ws + 339620;         // 500
    float* xp2    = ws + 340120;         // 20000
    int*   keep   = (int*)(ws + 360120); // 1000
    int*   nidx   = (int*)(ws + 361120); // 1000
    int*   nsrc   = (int*)(ws + 362120); // 32000
    int*   ndst   = (int*)(ws + 394120); // 32000
    float* new_ew = ws + 426120;         // 32000

    float* out = (float*)d_out;

    k_lin0<<<8, 256, 0, stream>>>(x, w0, b0, h0, psum0);
    k_lin1<<<16, 256, 0, stream>>>(h0, w1, b1, g0, be0, psum0, h1, psum1);
    k_score1<<<250, 256, 0, stream>>>(h1, psum1, g1, be1, p1_wrel, p1_wroot, p1_b, t1, sc1);
    k_scatter1<<<16, 256, 0, stream>>>(ei, ea, t1, sc1);
    k_rank1<<<250, 256, 0, stream>>>(sc1, h1, psum1, g1, be1, xp1, keep, nidx);
    k_lin2a_remap<<<133, 256, 0, stream>>>(xp1, w2a, b2a, h2a, psum2a,
                                           ei, ea, keep, nidx, nsrc, ndst, new_ew);
    k_lin2b<<<20, 256, 0, stream>>>(h2a, psum2a, g2a, be2a, w2b, b2b, h2b, psum2b);
    k_score2<<<125, 256, 0, stream>>>(h2b, psum2b, g2b, be2b, p2_wrel, p2_wroot, p2_b, t2, sc2);
    k_scatter2<<<16, 256, 0, stream>>>(nsrc, ndst, new_ew, t2, sc2);
    k_rank2<<<125, 256, 0, stream>>>(sc2, h2b, psum2b, g2b, be2b, xp2);
    k_final<<<1, 256, 0, stream>>>(xp2, w3a, b3a, w3b, b3b, out);
}